// Round 1
// baseline (1077.846 us; speedup 1.0000x reference)
//
#include <hip/hip_runtime.h>
#include <math.h>

#define B_   64
#define S_   8
#define T_   8192
#define T3_  8166      // 8192 - 2 - 6 - 18
#define LCH  256       // time-chunk of final outputs
#define NC   32        // ceil(T3_/LCH): 31*256 + 230
#define EPS_ 1e-8f

// ---------------- K1: eeg 1x1 conv 64 -> 8, [B,T,64] -> [B,8,T] ----------------
__global__ __launch_bounds__(256) void k_eeg1x1(const float* __restrict__ eeg,
                                                const float* __restrict__ w,
                                                const float* __restrict__ bias,
                                                float* __restrict__ x0) {
    __shared__ float ws[512];
    __shared__ float bs[8];
    int tid = threadIdx.x;
    ws[tid]       = w[tid];
    ws[tid + 256] = w[tid + 256];
    if (tid < 8) bs[tid] = bias[tid];
    __syncthreads();

    int gt = blockIdx.x * 256 + tid;      // b*T + t, < B*T = 524288
    int b  = gt >> 13;
    int t  = gt & (T_ - 1);
    const float* ep = eeg + (size_t)gt * 64;

    float acc[8];
#pragma unroll
    for (int c = 0; c < 8; ++c) acc[c] = bs[c];
#pragma unroll
    for (int i = 0; i < 64; i += 4) {
        float4 v = *(const float4*)(ep + i);
#pragma unroll
        for (int c = 0; c < 8; ++c) {
            const float* wp = ws + c * 64 + i;
            acc[c] += v.x * wp[0] + v.y * wp[1] + v.z * wp[2] + v.w * wp[3];
        }
    }
    float* op = x0 + (size_t)b * 8 * T_ + t;
#pragma unroll
    for (int c = 0; c < 8; ++c) op[(size_t)c * T_] = acc[c];
}

// ---------------- K2: eeg dilated stack 8->16->16->16 (d=1,3,9), fused per chunk ----------------
__global__ __launch_bounds__(256) void k_eeg_stack(const float* __restrict__ x0,
                                                   const float* __restrict__ w1, const float* __restrict__ b1,
                                                   const float* __restrict__ w2, const float* __restrict__ b2,
                                                   const float* __restrict__ w3, const float* __restrict__ b3,
                                                   float* __restrict__ x3) {
    const int SIN = 284, SA = 284, SB = 284;
    __shared__ __align__(16) float sin_[8 * 284];
    __shared__ __align__(16) float i1[16 * 284];
    __shared__ __align__(16) float i2[16 * 284];

    int tid   = threadIdx.x;
    int chunk = blockIdx.x;
    int b     = blockIdx.y;
    int c0    = chunk * LCH;
    int Lv    = min(LCH, T3_ - c0);

    // stage input chunk: 8 channels x (Lv+26)
    const float* src = x0 + (size_t)b * 8 * T_ + c0;
    for (int ci = 0; ci < 8; ++ci)
        for (int w = tid; w < Lv + 26; w += 256)
            sin_[ci * SIN + w] = src[(size_t)ci * T_ + w];
    __syncthreads();

    // conv1: d=1, cin=8
    {
        int n = Lv + 24;
        for (int co = 0; co < 16; ++co) {
            float bb = b1[co];
            for (int v = tid; v < n; v += 256) {
                float acc = bb;
#pragma unroll
                for (int ci = 0; ci < 8; ++ci) {
                    const float* wp = w1 + (co * 8 + ci) * 3;
                    const float* sp = sin_ + ci * SIN + v;
                    acc += sp[0] * wp[0] + sp[1] * wp[1] + sp[2] * wp[2];
                }
                i1[co * SA + v] = fmaxf(acc, 0.f);
            }
        }
    }
    __syncthreads();

    // conv2: d=3, cin=16
    {
        int n = Lv + 18;
        for (int co = 0; co < 16; ++co) {
            float bb = b2[co];
            for (int v = tid; v < n; v += 256) {
                float acc = bb;
#pragma unroll
                for (int ci = 0; ci < 16; ++ci) {
                    const float* wp = w2 + (co * 16 + ci) * 3;
                    const float* sp = i1 + ci * SA + v;
                    acc += sp[0] * wp[0] + sp[3] * wp[1] + sp[6] * wp[2];
                }
                i2[co * SB + v] = fmaxf(acc, 0.f);
            }
        }
    }
    __syncthreads();

    // conv3: d=9, cin=16 -> global x3
    {
        float* dst = x3 + (size_t)b * 16 * T3_ + c0;
        for (int co = 0; co < 16; ++co) {
            float bb = b3[co];
            for (int u = tid; u < Lv; u += 256) {
                float acc = bb;
#pragma unroll
                for (int ci = 0; ci < 16; ++ci) {
                    const float* wp = w3 + (co * 16 + ci) * 3;
                    const float* sp = i2 + ci * SB + u;
                    acc += sp[0] * wp[0] + sp[9] * wp[1] + sp[18] * wp[2];
                }
                dst[(size_t)co * T3_ + u] = fmaxf(acc, 0.f);
            }
        }
    }
}

// ---------------- K3: eeg channel norms, one block per (b,j) ----------------
__global__ __launch_bounds__(256) void k_nx(const float* __restrict__ x3, float* __restrict__ nx) {
    int bj = blockIdx.x;               // b*16 + j
    const float* p = x3 + (size_t)bj * T3_;
    int tid = threadIdx.x;
    float acc = 0.f;
    for (int t = tid; t < T3_; t += 256) { float v = p[t]; acc += v * v; }
#pragma unroll
    for (int m = 32; m > 0; m >>= 1) acc += __shfl_down(acc, m, 64);
    __shared__ float part[4];
    if ((tid & 63) == 0) part[tid >> 6] = acc;
    __syncthreads();
    if (tid == 0) nx[bj] = fmaxf(sqrtf(part[0] + part[1] + part[2] + part[3]), EPS_);
}

// ---------------- K4: stim fused stack + cosine dot + linear head, one block per (b,s) ----------------
__global__ __launch_bounds__(256) void k_stim(const float* __restrict__ stim,
                                              const float* __restrict__ w1, const float* __restrict__ b1,
                                              const float* __restrict__ w2, const float* __restrict__ b2,
                                              const float* __restrict__ w3, const float* __restrict__ b3,
                                              const float* __restrict__ x3, const float* __restrict__ nx,
                                              const float* __restrict__ wlin, const float* __restrict__ blin,
                                              float* __restrict__ out) {
    const int SA = 284, SB = 284, S3 = 260;
    __shared__ __align__(16) float sin_[LCH + 26];
    __shared__ __align__(16) float i1[16 * 284];
    __shared__ __align__(16) float i2[16 * 284];
    __shared__ __align__(16) float st3[16 * 260];
    __shared__ __align__(16) float x3t[16 * 260];
    __shared__ float red[4];

    int tid = threadIdx.x;
    int b = blockIdx.x >> 3, s = blockIdx.x & 7;
    int i = tid >> 4, j = tid & 15;

    const float* seq = stim + (size_t)(b * 8 + s) * T_;
    const float* xg  = x3 + (size_t)b * 16 * T3_;

    float dotr = 0.f, nstp = 0.f;

    for (int chunk = 0; chunk < NC; ++chunk) {
        int c0 = chunk * LCH;
        int Lv = min(LCH, T3_ - c0);

        for (int w = tid; w < Lv + 26; w += 256) sin_[w] = seq[c0 + w];
        __syncthreads();

        // conv1: cin=1, d=1
        {
            int n = Lv + 24;
            for (int co = 0; co < 16; ++co) {
                float wa = w1[co * 3], wb = w1[co * 3 + 1], wc = w1[co * 3 + 2], bb = b1[co];
                for (int v = tid; v < n; v += 256)
                    i1[co * SA + v] = fmaxf(bb + sin_[v] * wa + sin_[v + 1] * wb + sin_[v + 2] * wc, 0.f);
            }
        }
        __syncthreads();

        // conv2: d=3
        {
            int n = Lv + 18;
            for (int co = 0; co < 16; ++co) {
                float bb = b2[co];
                for (int v = tid; v < n; v += 256) {
                    float acc = bb;
#pragma unroll
                    for (int ci = 0; ci < 16; ++ci) {
                        const float* wp = w2 + (co * 16 + ci) * 3;
                        const float* sp = i1 + ci * SA + v;
                        acc += sp[0] * wp[0] + sp[3] * wp[1] + sp[6] * wp[2];
                    }
                    i2[co * SB + v] = fmaxf(acc, 0.f);
                }
            }
        }
        __syncthreads();

        // conv3: d=9 -> st3 (LDS), and stage x3 tile
        {
            for (int co = 0; co < 16; ++co) {
                float bb = b3[co];
                for (int u = tid; u < Lv; u += 256) {
                    float acc = bb;
#pragma unroll
                    for (int ci = 0; ci < 16; ++ci) {
                        const float* wp = w3 + (co * 16 + ci) * 3;
                        const float* sp = i2 + ci * SB + u;
                        acc += sp[0] * wp[0] + sp[9] * wp[1] + sp[18] * wp[2];
                    }
                    st3[co * S3 + u] = fmaxf(acc, 0.f);
                }
            }
            for (int jj = 0; jj < 16; ++jj)
                for (int u = tid; u < Lv; u += 256)
                    x3t[jj * S3 + u] = xg[(size_t)jj * T3_ + c0 + u];
        }
        __syncthreads();

        // norm partial: threads sharing i cover u strided by 16
        for (int u = j; u < Lv; u += 16) { float v = st3[i * S3 + u]; nstp += v * v; }

        // dot accumulation: thread (i,j)
        {
            const float* ap = st3 + i * S3;
            const float* bp = x3t + j * S3;
            int u = 0;
            for (; u + 4 <= Lv; u += 4) {
                float4 a = *(const float4*)(ap + u);
                float4 x = *(const float4*)(bp + u);
                dotr += a.x * x.x + a.y * x.y + a.z * x.z + a.w * x.w;
            }
            for (; u < Lv; ++u) dotr += ap[u] * bp[u];
        }
        __syncthreads();
    }

    // reduce nstp across the 16 threads sharing i (consecutive lanes in-wave)
#pragma unroll
    for (int m = 1; m < 16; m <<= 1) nstp += __shfl_xor(nstp, m, 64);
    float nst = fmaxf(sqrtf(nstp), EPS_);
    float nxj = nx[b * 16 + j];
    float contrib = (dotr / (nst * nxj)) * wlin[i * 16 + j];

#pragma unroll
    for (int m = 32; m > 0; m >>= 1) contrib += __shfl_down(contrib, m, 64);
    if ((tid & 63) == 0) red[tid >> 6] = contrib;
    __syncthreads();
    if (tid == 0) out[blockIdx.x] = red[0] + red[1] + red[2] + red[3] + blin[0];
}

extern "C" void kernel_launch(void* const* d_in, const int* in_sizes, int n_in,
                              void* d_out, int out_size, void* d_ws, size_t ws_size,
                              hipStream_t stream) {
    const float* eeg   = (const float*)d_in[0];
    const float* stim  = (const float*)d_in[1];
    const float* w_eeg = (const float*)d_in[2];
    const float* b_eeg = (const float*)d_in[3];
    const float* w_e1  = (const float*)d_in[4];
    const float* b_e1  = (const float*)d_in[5];
    const float* w_e2  = (const float*)d_in[6];
    const float* b_e2  = (const float*)d_in[7];
    const float* w_e3  = (const float*)d_in[8];
    const float* b_e3  = (const float*)d_in[9];
    const float* w_s1  = (const float*)d_in[10];
    const float* b_s1  = (const float*)d_in[11];
    const float* w_s2  = (const float*)d_in[12];
    const float* b_s2  = (const float*)d_in[13];
    const float* w_s3  = (const float*)d_in[14];
    const float* b_s3  = (const float*)d_in[15];
    const float* w_lin = (const float*)d_in[16];
    const float* b_lin = (const float*)d_in[17];

    float* ws = (float*)d_ws;
    float* x0 = ws;                        // B*8*T  = 4,194,304 floats
    float* x3 = ws + 4194304;              // B*16*T3 = 8,361,984 floats
    float* nx = x3 + 8361984;              // B*16 = 1024 floats
    float* out = (float*)d_out;            // B*S = 512 floats

    k_eeg1x1<<<(B_ * T_) / 256, 256, 0, stream>>>(eeg, w_eeg, b_eeg, x0);
    k_eeg_stack<<<dim3(NC, B_), 256, 0, stream>>>(x0, w_e1, b_e1, w_e2, b_e2, w_e3, b_e3, x3);
    k_nx<<<B_ * 16, 256, 0, stream>>>(x3, nx);
    k_stim<<<B_ * S_, 256, 0, stream>>>(stim, w_s1, b_s1, w_s2, b_s2, w_s3, b_s3,
                                        x3, nx, w_lin, b_lin, out);
}

// Round 2
// 245.444 us; speedup vs baseline: 4.3914x; 4.3914x over previous
//
#include <hip/hip_runtime.h>
#include <hip/hip_bf16.h>
#include <math.h>

#define B_   64
#define S_   8
#define T_   8192
#define T3_  8166      // 8192 - 26
#define T3P  8168      // padded row stride (16B-aligned rows)
#define LCH  256       // eeg-stack time chunk
#define NC   32        // ceil(T3/LCH)
#define EPS_ 1e-8f

typedef __bf16 bf16x8 __attribute__((ext_vector_type(8)));
typedef float  f32x4  __attribute__((ext_vector_type(4)));

__device__ __forceinline__ unsigned short f2bf(float x) {
    __hip_bfloat16 h = __float2bfloat16(x);
    return *reinterpret_cast<unsigned short*>(&h);
}
__device__ __forceinline__ float bf2f(unsigned short u) {
    unsigned int v = ((unsigned int)u) << 16;
    return *reinterpret_cast<float*>(&v);
}
__device__ __forceinline__ unsigned int pk2(float a, float b) {
    return (unsigned int)f2bf(a) | ((unsigned int)f2bf(b) << 16);
}

// ---------------- K1: eeg 1x1 conv 64 -> 8, [B,T,64] -> [B,8,T] (fp32) ----------------
__global__ __launch_bounds__(256) void k_eeg1x1(const float* __restrict__ eeg,
                                                const float* __restrict__ w,
                                                const float* __restrict__ bias,
                                                float* __restrict__ x0) {
    __shared__ float ws[512];
    __shared__ float bs[8];
    int tid = threadIdx.x;
    ws[tid]       = w[tid];
    ws[tid + 256] = w[tid + 256];
    if (tid < 8) bs[tid] = bias[tid];
    __syncthreads();

    int gt = blockIdx.x * 256 + tid;
    int b  = gt >> 13;
    int t  = gt & (T_ - 1);
    const float* ep = eeg + (size_t)gt * 64;

    float acc[8];
#pragma unroll
    for (int c = 0; c < 8; ++c) acc[c] = bs[c];
#pragma unroll
    for (int i = 0; i < 64; i += 4) {
        float4 v = *(const float4*)(ep + i);
#pragma unroll
        for (int c = 0; c < 8; ++c) {
            const float* wp = ws + c * 64 + i;
            acc[c] += v.x * wp[0] + v.y * wp[1] + v.z * wp[2] + v.w * wp[3];
        }
    }
    float* op = x0 + (size_t)b * 8 * T_ + t;
#pragma unroll
    for (int c = 0; c < 8; ++c) op[(size_t)c * T_] = acc[c];
}

// ---------------- K2: eeg dilated stack 8->16->16->16 (fp32 compute, bf16 store) ----------------
__global__ __launch_bounds__(256) void k_eeg_stack(const float* __restrict__ x0,
                                                   const float* __restrict__ w1, const float* __restrict__ b1,
                                                   const float* __restrict__ w2, const float* __restrict__ b2,
                                                   const float* __restrict__ w3, const float* __restrict__ b3,
                                                   unsigned short* __restrict__ x3b) {
    const int SIN = 284, SA = 284, SB = 284;
    __shared__ __align__(16) float sin_[8 * 284];
    __shared__ __align__(16) float i1[16 * 284];
    __shared__ __align__(16) float i2[16 * 284];

    int tid   = threadIdx.x;
    int chunk = blockIdx.x;
    int b     = blockIdx.y;
    int c0    = chunk * LCH;
    int Lv    = min(LCH, T3_ - c0);

    // zero the 2 pad columns once per (b)
    if (chunk == 0 && tid < 32)
        x3b[(size_t)b * 16 * T3P + (size_t)(tid >> 1) * T3P + T3_ + (tid & 1)] = 0;

    const float* src = x0 + (size_t)b * 8 * T_ + c0;
    for (int ci = 0; ci < 8; ++ci)
        for (int w = tid; w < Lv + 26; w += 256)
            sin_[ci * SIN + w] = src[(size_t)ci * T_ + w];
    __syncthreads();

    {   // conv1 d=1 cin=8
        int n = Lv + 24;
        for (int co = 0; co < 16; ++co) {
            float bb = b1[co];
            for (int v = tid; v < n; v += 256) {
                float acc = bb;
#pragma unroll
                for (int ci = 0; ci < 8; ++ci) {
                    const float* wp = w1 + (co * 8 + ci) * 3;
                    const float* sp = sin_ + ci * SIN + v;
                    acc += sp[0] * wp[0] + sp[1] * wp[1] + sp[2] * wp[2];
                }
                i1[co * SA + v] = fmaxf(acc, 0.f);
            }
        }
    }
    __syncthreads();

    {   // conv2 d=3
        int n = Lv + 18;
        for (int co = 0; co < 16; ++co) {
            float bb = b2[co];
            for (int v = tid; v < n; v += 256) {
                float acc = bb;
#pragma unroll
                for (int ci = 0; ci < 16; ++ci) {
                    const float* wp = w2 + (co * 16 + ci) * 3;
                    const float* sp = i1 + ci * SA + v;
                    acc += sp[0] * wp[0] + sp[3] * wp[1] + sp[6] * wp[2];
                }
                i2[co * SB + v] = fmaxf(acc, 0.f);
            }
        }
    }
    __syncthreads();

    {   // conv3 d=9 -> global bf16
        unsigned short* dst = x3b + (size_t)b * 16 * T3P + c0;
        for (int co = 0; co < 16; ++co) {
            float bb = b3[co];
            for (int u = tid; u < Lv; u += 256) {
                float acc = bb;
#pragma unroll
                for (int ci = 0; ci < 16; ++ci) {
                    const float* wp = w3 + (co * 16 + ci) * 3;
                    const float* sp = i2 + ci * SB + u;
                    acc += sp[0] * wp[0] + sp[9] * wp[1] + sp[18] * wp[2];
                }
                dst[(size_t)co * T3P + u] = f2bf(fmaxf(acc, 0.f));
            }
        }
    }
}

// ---------------- K3: eeg channel norms (bf16 input) ----------------
__global__ __launch_bounds__(256) void k_nx(const unsigned short* __restrict__ x3b, float* __restrict__ nx) {
    int bj = blockIdx.x;
    const unsigned short* p = x3b + (size_t)bj * T3P;
    int tid = threadIdx.x;
    float acc = 0.f;
    for (int t = tid; t < T3_; t += 256) { float v = bf2f(p[t]); acc += v * v; }
#pragma unroll
    for (int m = 32; m > 0; m >>= 1) acc += __shfl_down(acc, m, 64);
    __shared__ float part[4];
    if ((tid & 63) == 0) part[tid >> 6] = acc;
    __syncthreads();
    if (tid == 0) nx[bj] = fmaxf(sqrtf(part[0] + part[1] + part[2] + part[3]), EPS_);
}

// ---------------- K4: stim fused MFMA stack + dot partials ----------------
// grid (512, 4): blockIdx.x = b*8+s, blockIdx.y = chunk-group (4 chunks of 512)
__global__ __launch_bounds__(256) void k_stim(const float* __restrict__ stim,
                                              const float* __restrict__ w1, const float* __restrict__ b1,
                                              const float* __restrict__ w2, const float* __restrict__ b2,
                                              const float* __restrict__ w3, const float* __restrict__ b3,
                                              const unsigned short* __restrict__ x3b,
                                              float* __restrict__ dotp, float* __restrict__ nstp) {
    // LDS layout (bytes):
    //   0     sinb  float[544]            2176
    //   2176  Wl    ushort[4*512]         4096  -> 6272
    //   6272  i1T   ushort[560*16]        17920 -> 24192   (aliased by st3 ushort[16*536])
    //   24192 i2T   ushort[544*16]        17408 -> 41600
    __shared__ __align__(16) unsigned char smem[41600];
    float*          sinb = (float*)smem;
    unsigned short* Wl   = (unsigned short*)(smem + 2176);
    unsigned short* i1   = (unsigned short*)(smem + 6272);
    unsigned short* i2   = (unsigned short*)(smem + 24192);
    unsigned short* s3   = i1;   // alias (dead after conv2 consumed -> reused after conv3)

    int tid  = threadIdx.x;
    int bs   = blockIdx.x;
    int G    = blockIdx.y;
    int wv   = tid >> 6;        // wave 0..3
    int lane = tid & 63;
    int lm   = lane & 15;
    int lg   = lane >> 4;

    // ---- stage weight A-fragments (bf16) ----
    for (int idx = tid; idx < 2048; idx += 256) {
        int arr = idx >> 9, e = idx & 511;
        int m = e >> 5, k5 = e & 31;
        int ci = k5 & 15, tap = k5 >> 4;
        float v;
        if (arr == 0)      v = w2[(m * 16 + ci) * 3 + tap];          // taps 0,3
        else if (arr == 1) v = (k5 < 16) ? w2[(m * 16 + k5) * 3 + 2] : 0.f;  // tap 6
        else if (arr == 2) v = w3[(m * 16 + ci) * 3 + tap];          // taps 0,9
        else               v = (k5 < 16) ? w3[(m * 16 + k5) * 3 + 2] : 0.f;  // tap 18
        Wl[idx] = f2bf(v);
    }
    __syncthreads();
    const bf16x8 W2a = *(const bf16x8*)(Wl +         lm * 32 + 8 * lg);
    const bf16x8 W2b = *(const bf16x8*)(Wl + 512  +  lm * 32 + 8 * lg);
    const bf16x8 W3a = *(const bf16x8*)(Wl + 1024 +  lm * 32 + 8 * lg);
    const bf16x8 W3b = *(const bf16x8*)(Wl + 1536 +  lm * 32 + 8 * lg);
    f32x4 cin2, cin3;
#pragma unroll
    for (int r = 0; r < 4; ++r) { cin2[r] = b2[4 * lg + r]; cin3[r] = b3[4 * lg + r]; }

    const float* seq = stim + (size_t)bs * T_;
    int b16 = (bs >> 3) * 16;

    f32x4 dacc;
#pragma unroll
    for (int r = 0; r < 4; ++r) dacc[r] = 0.f;
    float nst[4] = {0.f, 0.f, 0.f, 0.f};

    for (int cc = 0; cc < 4; ++cc) {
        int c0 = (G * 4 + cc) * 512;
        int Lv = min(512, T3_ - c0);
        int n1 = Lv + 24;

        __syncthreads();   // prev chunk's dot (reads s3=i1) done before we overwrite

        // ---- stage stim chunk (fp32) ----
        for (int t = tid; t < Lv + 26; t += 256) sinb[t] = seq[c0 + t];
        __syncthreads();

        // ---- conv1 (VALU, cin=1): sinb -> i1T[v][16] bf16 ----
        for (int v = tid; v < n1; v += 256) {
            float s0 = sinb[v], s1 = sinb[v + 1], s2 = sinb[v + 2];
            float a[16];
#pragma unroll
            for (int co = 0; co < 16; ++co)
                a[co] = fmaxf(b1[co] + s0 * w1[co * 3] + s1 * w1[co * 3 + 1] + s2 * w1[co * 3 + 2], 0.f);
            uint4 p0, p1;
            p0.x = pk2(a[0], a[1]);   p0.y = pk2(a[2], a[3]);
            p0.z = pk2(a[4], a[5]);   p0.w = pk2(a[6], a[7]);
            p1.x = pk2(a[8], a[9]);   p1.y = pk2(a[10], a[11]);
            p1.z = pk2(a[12], a[13]); p1.w = pk2(a[14], a[15]);
            *(uint4*)(i1 + v * 16)     = p0;
            *(uint4*)(i1 + v * 16 + 8) = p1;
        }
        // zero-fill i1T rows [n1, 560)
        for (int z = tid; z < (560 - n1) * 8; z += 256)
            ((unsigned int*)i1)[n1 * 8 + z] = 0;
        __syncthreads();

        // ---- conv2 (MFMA): i1T -> i2T ----
        for (int ub = wv; ub < 34; ub += 4) {
            int u = ub * 16 + lm;
            int t3 = 3 * (lg >> 1);
            bf16x8 Ba = *(const bf16x8*)(i1 + (u + t3) * 16 + (lg & 1) * 8);
            bf16x8 Bb = *(const bf16x8*)(i1 + (u + 6 + t3) * 16 + (lg & 1) * 8);
            f32x4 acc = cin2;
            acc = __builtin_amdgcn_mfma_f32_16x16x32_bf16(W2a, Ba, acc, 0, 0, 0);
            acc = __builtin_amdgcn_mfma_f32_16x16x32_bf16(W2b, Bb, acc, 0, 0, 0);
            uint2 pq;
            pq.x = pk2(fmaxf(acc[0], 0.f), fmaxf(acc[1], 0.f));
            pq.y = pk2(fmaxf(acc[2], 0.f), fmaxf(acc[3], 0.f));
            *(uint2*)(i2 + u * 16 + lg * 4) = pq;
        }
        __syncthreads();

        // ---- conv3 (MFMA): i2T -> st3[16][536] bf16 (masked beyond Lv) + norm partials ----
        for (int ub = wv; ub < 32; ub += 4) {
            int u = ub * 16 + lm;
            int t9 = 9 * (lg >> 1);
            bf16x8 Ba = *(const bf16x8*)(i2 + (u + t9) * 16 + (lg & 1) * 8);
            bf16x8 Bb = *(const bf16x8*)(i2 + (u + 18 + t9) * 16 + (lg & 1) * 8);
            f32x4 acc = cin3;
            acc = __builtin_amdgcn_mfma_f32_16x16x32_bf16(W3a, Ba, acc, 0, 0, 0);
            acc = __builtin_amdgcn_mfma_f32_16x16x32_bf16(W3b, Bb, acc, 0, 0, 0);
            bool ok = (u < Lv);
#pragma unroll
            for (int r = 0; r < 4; ++r) {
                float v = ok ? fmaxf(acc[r], 0.f) : 0.f;
                nst[r] += v * v;
                s3[(4 * lg + r) * 536 + u] = f2bf(v);
            }
        }
        __syncthreads();

        // ---- dot (MFMA): dacc[i][j] += st3 . x3^T, waves split K (t) ----
#pragma unroll
        for (int kk = 0; kk < 4; ++kk) {
            int tl = wv * 128 + kk * 32 + 8 * lg;
            bf16x8 Af = *(const bf16x8*)(s3 + lm * 536 + tl);
            int tg = c0 + tl;
            int tc = (tg > 8160) ? 0 : tg;      // clamped lanes have A==0
            bf16x8 Bf = *(const bf16x8*)(x3b + (size_t)(b16 + lm) * T3P + tc);
            dacc = __builtin_amdgcn_mfma_f32_16x16x32_bf16(Af, Bf, dacc, 0, 0, 0);
        }
    }

    // ---- write partials ----
#pragma unroll
    for (int r = 0; r < 4; ++r) {
        float t = nst[r];
        t += __shfl_xor(t, 1); t += __shfl_xor(t, 2);
        t += __shfl_xor(t, 4); t += __shfl_xor(t, 8);
        nst[r] = t;
    }
    int ob = (bs * 4 + G) * 4 + wv;
    *(f32x4*)(dotp + (size_t)ob * 256 + lane * 4) = dacc;
    if (lm == 0) {
#pragma unroll
        for (int r = 0; r < 4; ++r) nstp[(size_t)ob * 16 + 4 * lg + r] = nst[r];
    }
}

// ---------------- K5: reduce partials, cosine, linear head ----------------
__global__ __launch_bounds__(256) void k_head(const float* __restrict__ dotp,
                                              const float* __restrict__ nstp,
                                              const float* __restrict__ nx,
                                              const float* __restrict__ wlin,
                                              const float* __restrict__ blin,
                                              float* __restrict__ out) {
    int bs = blockIdx.x, tid = threadIdx.x;
    int i = 4 * (tid >> 6) + (tid & 3);
    int j = (tid >> 2) & 15;
    float dot = 0.f, ss = 0.f;
#pragma unroll
    for (int gw = 0; gw < 16; ++gw) {
        dot += dotp[(size_t)(bs * 16 + gw) * 256 + tid];
        ss  += nstp[(size_t)(bs * 16 + gw) * 16 + i];
    }
    float nstv = fmaxf(sqrtf(ss), EPS_);
    float val = dot / (nstv * nx[(bs >> 3) * 16 + j]) * wlin[i * 16 + j];
#pragma unroll
    for (int m = 32; m > 0; m >>= 1) val += __shfl_down(val, m, 64);
    __shared__ float rd[4];
    if ((tid & 63) == 0) rd[tid >> 6] = val;
    __syncthreads();
    if (tid == 0) out[bs] = rd[0] + rd[1] + rd[2] + rd[3] + blin[0];
}

extern "C" void kernel_launch(void* const* d_in, const int* in_sizes, int n_in,
                              void* d_out, int out_size, void* d_ws, size_t ws_size,
                              hipStream_t stream) {
    const float* eeg   = (const float*)d_in[0];
    const float* stim  = (const float*)d_in[1];
    const float* w_eeg = (const float*)d_in[2];
    const float* b_eeg = (const float*)d_in[3];
    const float* w_e1  = (const float*)d_in[4];
    const float* b_e1  = (const float*)d_in[5];
    const float* w_e2  = (const float*)d_in[6];
    const float* b_e2  = (const float*)d_in[7];
    const float* w_e3  = (const float*)d_in[8];
    const float* b_e3  = (const float*)d_in[9];
    const float* w_s1  = (const float*)d_in[10];
    const float* b_s1  = (const float*)d_in[11];
    const float* w_s2  = (const float*)d_in[12];
    const float* b_s2  = (const float*)d_in[13];
    const float* w_s3  = (const float*)d_in[14];
    const float* b_s3  = (const float*)d_in[15];
    const float* w_lin = (const float*)d_in[16];
    const float* b_lin = (const float*)d_in[17];

    unsigned char* ws = (unsigned char*)d_ws;
    float*          x0   = (float*)ws;                                  // 16,777,216 B
    unsigned short* x3b  = (unsigned short*)(ws + 16777216);            // 16,728,064 B
    float*          nx   = (float*)(ws + 33505280);                     // 4,096 B
    float*          dotp = (float*)(ws + 33509376);                     // 8,388,608 B
    float*          nstp = (float*)(ws + 41897984);                     // 524,288 B
    float*          out  = (float*)d_out;

    k_eeg1x1<<<(B_ * T_) / 256, 256, 0, stream>>>(eeg, w_eeg, b_eeg, x0);
    k_eeg_stack<<<dim3(NC, B_), 256, 0, stream>>>(x0, w_e1, b_e1, w_e2, b_e2, w_e3, b_e3, x3b);
    k_nx<<<B_ * 16, 256, 0, stream>>>(x3b, nx);
    k_stim<<<dim3(B_ * S_, 4), 256, 0, stream>>>(stim, w_s1, b_s1, w_s2, b_s2, w_s3, b_s3,
                                                 x3b, dotp, nstp);
    k_head<<<B_ * S_, 256, 0, stream>>>(dotp, nstp, nx, w_lin, b_lin, out);
}

// Round 3
// 184.732 us; speedup vs baseline: 5.8347x; 1.3286x over previous
//
#include <hip/hip_runtime.h>
#include <hip/hip_bf16.h>
#include <math.h>

#define B_   64
#define S_   8
#define T_   8192
#define T3_  8166      // 8192 - 26
#define T3P  8168      // padded row stride
#define EPS_ 1e-8f

typedef __bf16 bf16x8 __attribute__((ext_vector_type(8)));
typedef float  f32x4  __attribute__((ext_vector_type(4)));

__device__ __forceinline__ unsigned short f2bf(float x) {
    __hip_bfloat16 h = __float2bfloat16(x);
    return *reinterpret_cast<unsigned short*>(&h);
}
__device__ __forceinline__ unsigned int pk2(float a, float b) {
    return (unsigned int)f2bf(a) | ((unsigned int)f2bf(b) << 16);
}
__device__ __forceinline__ bf16x8 as_bf(uint4 u) { return *reinterpret_cast<bf16x8*>(&u); }

// =========== K_EEG: fused eeg path: 1x1(64->8) + dilated stack -> x3b bf16 + norm partials ===========
// grid (16 chunks, 64 b), 256 threads
__global__ __launch_bounds__(256) void k_eeg(const float* __restrict__ eeg,
        const float* __restrict__ wx, const float* __restrict__ bx,
        const float* __restrict__ w1, const float* __restrict__ b1,
        const float* __restrict__ w2, const float* __restrict__ b2,
        const float* __restrict__ w3, const float* __restrict__ b3,
        unsigned short* __restrict__ x3b, float* __restrict__ nxp) {
    // LDS: x0T u16[560*8] @0 ; i1 u16[560*16] @8960 ; i2 u16[544*16] @26880 ; wred f32[64] @44288
    // aliases: Wst(=i1 head, 3584 u16) ; st3 u16[16*520] @0 (over x0T + i1 head, both dead by conv3)
    __shared__ __align__(16) unsigned char smem[44544];
    unsigned short* x0T = (unsigned short*)smem;
    unsigned short* i1  = (unsigned short*)(smem + 8960);
    unsigned short* i2  = (unsigned short*)(smem + 26880);
    float*          wred= (float*)(smem + 44288);
    unsigned short* st3 = (unsigned short*)smem;
    unsigned short* Wst = i1;

    int tid = threadIdx.x;
    int chunk = blockIdx.x, b = blockIdx.y;
    int wv = tid >> 6, lane = tid & 63, lm = lane & 15, lg = lane >> 4;

    int c0 = chunk * 512;
    int Lv = min(512, T3_ - c0);
    int n_in = Lv + 26, n1 = Lv + 24, n2 = Lv + 18;
    int nub_in = (n_in + 15) >> 4, nub1 = (n1 + 15) >> 4, nub2 = (n2 + 15) >> 4, nub3 = (Lv + 15) >> 4;

    // ---- stage weight fragments (bf16) into Wst ----
    for (int idx = tid; idx < 3584; idx += 256) {
        int arr = idx >> 9, e = idx & 511;
        int m = e >> 5, k5 = e & 31;
        float v = 0.f;
        if (arr == 0)      { if (m < 8) v = wx[m * 64 + k5]; }
        else if (arr == 1) { if (m < 8) v = wx[m * 64 + 32 + k5]; }
        else if (arr == 2) { int tap = k5 >> 3, ci = k5 & 7; if (tap < 3) v = w1[(m * 8 + ci) * 3 + tap]; }
        else if (arr == 3) { int tap = k5 >> 4, ci = k5 & 15; v = w2[(m * 16 + ci) * 3 + tap]; }
        else if (arr == 4) { if (k5 < 16) v = w2[(m * 16 + k5) * 3 + 2]; }
        else if (arr == 5) { int tap = k5 >> 4, ci = k5 & 15; v = w3[(m * 16 + ci) * 3 + tap]; }
        else               { if (k5 < 16) v = w3[(m * 16 + k5) * 3 + 2]; }
        Wst[idx] = f2bf(v);
    }
    // ---- zero LDS tails (NaN-safety for pad-A reads) ----
    for (int idx = tid; idx < (560 - n_in) * 4; idx += 256)
        ((unsigned int*)(x0T + n_in * 8))[idx] = 0;
    {
        int z0 = nub1 * 16;
        for (int idx = tid; idx < (560 - z0) * 8; idx += 256)
            ((unsigned int*)(i1 + z0 * 16))[idx] = 0;
        int z2 = nub2 * 16;
        for (int idx = tid; idx < (544 - z2) * 8; idx += 256)
            ((unsigned int*)(i2 + z2 * 16))[idx] = 0;
    }
    __syncthreads();

    const bf16x8 Wxa = *(const bf16x8*)(Wst +        lm * 32 + 8 * lg);
    const bf16x8 Wxb = *(const bf16x8*)(Wst + 512  + lm * 32 + 8 * lg);
    const bf16x8 W1f = *(const bf16x8*)(Wst + 1024 + lm * 32 + 8 * lg);
    const bf16x8 W2a = *(const bf16x8*)(Wst + 1536 + lm * 32 + 8 * lg);
    const bf16x8 W2b = *(const bf16x8*)(Wst + 2048 + lm * 32 + 8 * lg);
    const bf16x8 W3a = *(const bf16x8*)(Wst + 2560 + lm * 32 + 8 * lg);
    const bf16x8 W3b = *(const bf16x8*)(Wst + 3072 + lm * 32 + 8 * lg);
    f32x4 cx, c1v, c2v, c3v;
#pragma unroll
    for (int r = 0; r < 4; ++r) {
        int m = 4 * lg + r;
        cx[r]  = (m < 8) ? bx[m] : 0.f;
        c1v[r] = b1[m]; c2v[r] = b2[m]; c3v[r] = b3[m];
    }

    // ---- (a) 1x1 conv via MFMA, B-frags straight from global eeg ----
    {
        const float* ebase = eeg + ((size_t)b * T_ + c0) * 64;
        for (int ub = wv; ub < nub_in; ub += 4) {
            int t = ub * 16 + lm;
            bool vld = t < n_in;
            const float* ep = ebase + (size_t)t * 64 + 8 * lg;
            float4 z = {0.f, 0.f, 0.f, 0.f};
            float4 aa = vld ? *(const float4*)(ep)      : z;
            float4 ab = vld ? *(const float4*)(ep + 4)  : z;
            float4 ba = vld ? *(const float4*)(ep + 32) : z;
            float4 bb = vld ? *(const float4*)(ep + 36) : z;
            uint4 pa = { pk2(aa.x, aa.y), pk2(aa.z, aa.w), pk2(ab.x, ab.y), pk2(ab.z, ab.w) };
            uint4 pb = { pk2(ba.x, ba.y), pk2(ba.z, ba.w), pk2(bb.x, bb.y), pk2(bb.z, bb.w) };
            f32x4 acc = cx;
            acc = __builtin_amdgcn_mfma_f32_16x16x32_bf16(Wxa, as_bf(pa), acc, 0, 0, 0);
            acc = __builtin_amdgcn_mfma_f32_16x16x32_bf16(Wxb, as_bf(pb), acc, 0, 0, 0);
            if (lg < 2 && vld) {   // co = 4lg+r < 8 only; NO relu on the 1x1
                uint2 pq = { pk2(acc[0], acc[1]), pk2(acc[2], acc[3]) };
                *(uint2*)(x0T + t * 8 + lg * 4) = pq;
            }
        }
    }
    __syncthreads();

    // ---- (b) conv1 d=1 cin=8 (one MFMA: taps 0,1,2 + pad) ----
    for (int ub = wv; ub < nub1; ub += 4) {
        int u = ub * 16 + lm;
        bf16x8 Ba = *(const bf16x8*)(x0T + (u + lg) * 8);   // lg==3 slot has A==0
        f32x4 acc = __builtin_amdgcn_mfma_f32_16x16x32_bf16(W1f, Ba, c1v, 0, 0, 0);
        uint2 pq = { pk2(fmaxf(acc[0], 0.f), fmaxf(acc[1], 0.f)),
                     pk2(fmaxf(acc[2], 0.f), fmaxf(acc[3], 0.f)) };
        *(uint2*)(i1 + u * 16 + lg * 4) = pq;
    }
    __syncthreads();

    // ---- (c) conv2 d=3 ----
    for (int ub = wv; ub < nub2; ub += 4) {
        int u = ub * 16 + lm;
        int t3 = 3 * (lg >> 1);
        bf16x8 Ba = *(const bf16x8*)(i1 + (u + t3) * 16 + (lg & 1) * 8);
        bf16x8 Bb = *(const bf16x8*)(i1 + (u + 6 + t3) * 16 + (lg & 1) * 8);
        f32x4 acc = c2v;
        acc = __builtin_amdgcn_mfma_f32_16x16x32_bf16(W2a, Ba, acc, 0, 0, 0);
        acc = __builtin_amdgcn_mfma_f32_16x16x32_bf16(W2b, Bb, acc, 0, 0, 0);
        uint2 pq = { pk2(fmaxf(acc[0], 0.f), fmaxf(acc[1], 0.f)),
                     pk2(fmaxf(acc[2], 0.f), fmaxf(acc[3], 0.f)) };
        *(uint2*)(i2 + u * 16 + lg * 4) = pq;
    }
    __syncthreads();

    // ---- (d) conv3 d=9 -> st3 + norm partials ----
    float nst[4] = {0.f, 0.f, 0.f, 0.f};
    for (int ub = wv; ub < nub3; ub += 4) {
        int u = ub * 16 + lm;
        int t9 = 9 * (lg >> 1);
        bf16x8 Ba = *(const bf16x8*)(i2 + (u + t9) * 16 + (lg & 1) * 8);
        bf16x8 Bb = *(const bf16x8*)(i2 + (u + 18 + t9) * 16 + (lg & 1) * 8);
        f32x4 acc = c3v;
        acc = __builtin_amdgcn_mfma_f32_16x16x32_bf16(W3a, Ba, acc, 0, 0, 0);
        acc = __builtin_amdgcn_mfma_f32_16x16x32_bf16(W3b, Bb, acc, 0, 0, 0);
        bool ok = u < Lv;
#pragma unroll
        for (int r = 0; r < 4; ++r) {
            float v = ok ? fmaxf(acc[r], 0.f) : 0.f;
            nst[r] += v * v;
            st3[(4 * lg + r) * 520 + u] = f2bf(v);
        }
    }
    // norm reduce across lm, then across waves via wred
#pragma unroll
    for (int r = 0; r < 4; ++r) {
        float t = nst[r];
        t += __shfl_xor(t, 1); t += __shfl_xor(t, 2);
        t += __shfl_xor(t, 4); t += __shfl_xor(t, 8);
        nst[r] = t;
    }
    if (lm == 0) {
#pragma unroll
        for (int r = 0; r < 4; ++r) wred[wv * 16 + 4 * lg + r] = nst[r];
    }
    __syncthreads();

    if (tid < 16) {
        float s = wred[tid] + wred[16 + tid] + wred[32 + tid] + wred[48 + tid];
        nxp[((size_t)b * 16 + tid) * 16 + chunk] = s;
    }
    // ---- (e) coalesced st3 -> x3b ----
    {
        unsigned short* dst = x3b + (size_t)(b * 16) * T3P + c0;
        for (int idx = tid; idx < 16 * 64; idx += 256) {
            int co = idx >> 6, off = (idx & 63) * 8;
            if (off + 8 <= Lv)
                *(uint4*)(dst + (size_t)co * T3P + off) = *(const uint4*)(st3 + co * 520 + off);
            else
                for (int k = off; k < Lv; ++k) dst[(size_t)co * T3P + k] = st3[co * 520 + k];
        }
        if (chunk == 15 && tid < 16)
            *(unsigned int*)(x3b + (size_t)(b * 16 + tid) * T3P + T3_) = 0;   // zero pad cols
    }
}

// =========== K4: stim fused MFMA stack + dot partials (unchanged from R2) ===========
__global__ __launch_bounds__(256) void k_stim(const float* __restrict__ stim,
                                              const float* __restrict__ w1, const float* __restrict__ b1,
                                              const float* __restrict__ w2, const float* __restrict__ b2,
                                              const float* __restrict__ w3, const float* __restrict__ b3,
                                              const unsigned short* __restrict__ x3b,
                                              float* __restrict__ dotp, float* __restrict__ nstp) {
    __shared__ __align__(16) unsigned char smem[41600];
    float*          sinb = (float*)smem;
    unsigned short* Wl   = (unsigned short*)(smem + 2176);
    unsigned short* i1   = (unsigned short*)(smem + 6272);
    unsigned short* i2   = (unsigned short*)(smem + 24192);
    unsigned short* s3   = i1;

    int tid  = threadIdx.x;
    int bs   = blockIdx.x;
    int G    = blockIdx.y;
    int wv   = tid >> 6;
    int lane = tid & 63;
    int lm   = lane & 15;
    int lg   = lane >> 4;

    for (int idx = tid; idx < 2048; idx += 256) {
        int arr = idx >> 9, e = idx & 511;
        int m = e >> 5, k5 = e & 31;
        int ci = k5 & 15, tap = k5 >> 4;
        float v;
        if (arr == 0)      v = w2[(m * 16 + ci) * 3 + tap];
        else if (arr == 1) v = (k5 < 16) ? w2[(m * 16 + k5) * 3 + 2] : 0.f;
        else if (arr == 2) v = w3[(m * 16 + ci) * 3 + tap];
        else               v = (k5 < 16) ? w3[(m * 16 + k5) * 3 + 2] : 0.f;
        Wl[idx] = f2bf(v);
    }
    __syncthreads();
    const bf16x8 W2a = *(const bf16x8*)(Wl +         lm * 32 + 8 * lg);
    const bf16x8 W2b = *(const bf16x8*)(Wl + 512  +  lm * 32 + 8 * lg);
    const bf16x8 W3a = *(const bf16x8*)(Wl + 1024 +  lm * 32 + 8 * lg);
    const bf16x8 W3b = *(const bf16x8*)(Wl + 1536 +  lm * 32 + 8 * lg);
    f32x4 cin2, cin3;
#pragma unroll
    for (int r = 0; r < 4; ++r) { cin2[r] = b2[4 * lg + r]; cin3[r] = b3[4 * lg + r]; }

    const float* seq = stim + (size_t)bs * T_;
    int b16 = (bs >> 3) * 16;

    f32x4 dacc;
#pragma unroll
    for (int r = 0; r < 4; ++r) dacc[r] = 0.f;
    float nst[4] = {0.f, 0.f, 0.f, 0.f};

    for (int cc = 0; cc < 4; ++cc) {
        int c0 = (G * 4 + cc) * 512;
        int Lv = min(512, T3_ - c0);
        int n1 = Lv + 24;

        __syncthreads();

        for (int t = tid; t < Lv + 26; t += 256) sinb[t] = seq[c0 + t];
        __syncthreads();

        for (int v = tid; v < n1; v += 256) {
            float s0 = sinb[v], s1 = sinb[v + 1], s2 = sinb[v + 2];
            float a[16];
#pragma unroll
            for (int co = 0; co < 16; ++co)
                a[co] = fmaxf(b1[co] + s0 * w1[co * 3] + s1 * w1[co * 3 + 1] + s2 * w1[co * 3 + 2], 0.f);
            uint4 p0, p1;
            p0.x = pk2(a[0], a[1]);   p0.y = pk2(a[2], a[3]);
            p0.z = pk2(a[4], a[5]);   p0.w = pk2(a[6], a[7]);
            p1.x = pk2(a[8], a[9]);   p1.y = pk2(a[10], a[11]);
            p1.z = pk2(a[12], a[13]); p1.w = pk2(a[14], a[15]);
            *(uint4*)(i1 + v * 16)     = p0;
            *(uint4*)(i1 + v * 16 + 8) = p1;
        }
        for (int z = tid; z < (560 - n1) * 8; z += 256)
            ((unsigned int*)i1)[n1 * 8 + z] = 0;
        __syncthreads();

        for (int ub = wv; ub < 34; ub += 4) {
            int u = ub * 16 + lm;
            int t3 = 3 * (lg >> 1);
            bf16x8 Ba = *(const bf16x8*)(i1 + (u + t3) * 16 + (lg & 1) * 8);
            bf16x8 Bb = *(const bf16x8*)(i1 + (u + 6 + t3) * 16 + (lg & 1) * 8);
            f32x4 acc = cin2;
            acc = __builtin_amdgcn_mfma_f32_16x16x32_bf16(W2a, Ba, acc, 0, 0, 0);
            acc = __builtin_amdgcn_mfma_f32_16x16x32_bf16(W2b, Bb, acc, 0, 0, 0);
            uint2 pq;
            pq.x = pk2(fmaxf(acc[0], 0.f), fmaxf(acc[1], 0.f));
            pq.y = pk2(fmaxf(acc[2], 0.f), fmaxf(acc[3], 0.f));
            *(uint2*)(i2 + u * 16 + lg * 4) = pq;
        }
        __syncthreads();

        for (int ub = wv; ub < 32; ub += 4) {
            int u = ub * 16 + lm;
            int t9 = 9 * (lg >> 1);
            bf16x8 Ba = *(const bf16x8*)(i2 + (u + t9) * 16 + (lg & 1) * 8);
            bf16x8 Bb = *(const bf16x8*)(i2 + (u + 18 + t9) * 16 + (lg & 1) * 8);
            f32x4 acc = cin3;
            acc = __builtin_amdgcn_mfma_f32_16x16x32_bf16(W3a, Ba, acc, 0, 0, 0);
            acc = __builtin_amdgcn_mfma_f32_16x16x32_bf16(W3b, Bb, acc, 0, 0, 0);
            bool ok = (u < Lv);
#pragma unroll
            for (int r = 0; r < 4; ++r) {
                float v = ok ? fmaxf(acc[r], 0.f) : 0.f;
                nst[r] += v * v;
                s3[(4 * lg + r) * 536 + u] = f2bf(v);
            }
        }
        __syncthreads();

#pragma unroll
        for (int kk = 0; kk < 4; ++kk) {
            int tl = wv * 128 + kk * 32 + 8 * lg;
            bf16x8 Af = *(const bf16x8*)(s3 + lm * 536 + tl);
            int tg = c0 + tl;
            int tc = (tg > 8160) ? 0 : tg;
            bf16x8 Bf = *(const bf16x8*)(x3b + (size_t)(b16 + lm) * T3P + tc);
            dacc = __builtin_amdgcn_mfma_f32_16x16x32_bf16(Af, Bf, dacc, 0, 0, 0);
        }
    }

#pragma unroll
    for (int r = 0; r < 4; ++r) {
        float t = nst[r];
        t += __shfl_xor(t, 1); t += __shfl_xor(t, 2);
        t += __shfl_xor(t, 4); t += __shfl_xor(t, 8);
        nst[r] = t;
    }
    int ob = (bs * 4 + G) * 4 + wv;
    *(f32x4*)(dotp + (size_t)ob * 256 + lane * 4) = dacc;
    if (lm == 0) {
#pragma unroll
        for (int r = 0; r < 4; ++r) nstp[(size_t)ob * 16 + 4 * lg + r] = nst[r];
    }
}

// =========== K5: reduce partials, cosine, linear head ===========
__global__ __launch_bounds__(256) void k_head(const float* __restrict__ dotp,
                                              const float* __restrict__ nstp,
                                              const float* __restrict__ nxp,
                                              const float* __restrict__ wlin,
                                              const float* __restrict__ blin,
                                              float* __restrict__ out) {
    int bs = blockIdx.x, tid = threadIdx.x;
    int b = bs >> 3;
    __shared__ float nxv[16];
    if (tid < 16) {
        float s = 0.f;
#pragma unroll
        for (int ch = 0; ch < 16; ++ch) s += nxp[((size_t)b * 16 + tid) * 16 + ch];
        nxv[tid] = fmaxf(sqrtf(s), EPS_);
    }
    __syncthreads();
    int i = 4 * (tid >> 6) + (tid & 3);
    int j = (tid >> 2) & 15;
    float dot = 0.f, ss = 0.f;
#pragma unroll
    for (int gw = 0; gw < 16; ++gw) {
        dot += dotp[(size_t)(bs * 16 + gw) * 256 + tid];
        ss  += nstp[(size_t)(bs * 16 + gw) * 16 + i];
    }
    float nstv = fmaxf(sqrtf(ss), EPS_);
    float val = dot / (nstv * nxv[j]) * wlin[i * 16 + j];
#pragma unroll
    for (int m = 32; m > 0; m >>= 1) val += __shfl_down(val, m, 64);
    __shared__ float rd[4];
    if ((tid & 63) == 0) rd[tid >> 6] = val;
    __syncthreads();
    if (tid == 0) out[bs] = rd[0] + rd[1] + rd[2] + rd[3] + blin[0];
}

extern "C" void kernel_launch(void* const* d_in, const int* in_sizes, int n_in,
                              void* d_out, int out_size, void* d_ws, size_t ws_size,
                              hipStream_t stream) {
    const float* eeg   = (const float*)d_in[0];
    const float* stim  = (const float*)d_in[1];
    const float* w_eeg = (const float*)d_in[2];
    const float* b_eeg = (const float*)d_in[3];
    const float* w_e1  = (const float*)d_in[4];
    const float* b_e1  = (const float*)d_in[5];
    const float* w_e2  = (const float*)d_in[6];
    const float* b_e2  = (const float*)d_in[7];
    const float* w_e3  = (const float*)d_in[8];
    const float* b_e3  = (const float*)d_in[9];
    const float* w_s1  = (const float*)d_in[10];
    const float* b_s1  = (const float*)d_in[11];
    const float* w_s2  = (const float*)d_in[12];
    const float* b_s2  = (const float*)d_in[13];
    const float* w_s3  = (const float*)d_in[14];
    const float* b_s3  = (const float*)d_in[15];
    const float* w_lin = (const float*)d_in[16];
    const float* b_lin = (const float*)d_in[17];

    unsigned char* ws = (unsigned char*)d_ws;
    unsigned short* x3b  = (unsigned short*)ws;                 // 16,728,064 B
    float*          nxp  = (float*)(ws + 16728064);             // 65,536 B
    float*          dotp = (float*)(ws + 16793600);             // 8,388,608 B
    float*          nstp = (float*)(ws + 25182208);             // 524,288 B
    float*          out  = (float*)d_out;

    k_eeg<<<dim3(16, B_), 256, 0, stream>>>(eeg, w_eeg, b_eeg, w_e1, b_e1, w_e2, b_e2,
                                            w_e3, b_e3, x3b, nxp);
    k_stim<<<dim3(B_ * S_, 4), 256, 0, stream>>>(stim, w_s1, b_s1, w_s2, b_s2, w_s3, b_s3,
                                                 x3b, dotp, nstp);
    k_head<<<B_ * S_, 256, 0, stream>>>(dotp, nstp, nxp, w_lin, b_lin, out);
}

// Round 4
// 143.523 us; speedup vs baseline: 7.5099x; 1.2871x over previous
//
#include <hip/hip_runtime.h>
#include <hip/hip_bf16.h>
#include <math.h>

#define B_   64
#define S_   8
#define T_   8192
#define T3_  8166      // 8192 - 26
#define T3P  8168      // padded row stride
#define EPS_ 1e-8f

typedef __bf16 bf16x8 __attribute__((ext_vector_type(8)));
typedef float  f32x4  __attribute__((ext_vector_type(4)));

__device__ __forceinline__ unsigned short f2bf(float x) {
    __hip_bfloat16 h = __float2bfloat16(x);
    return *reinterpret_cast<unsigned short*>(&h);
}
__device__ __forceinline__ unsigned int pk2(float a, float b) {
    return (unsigned int)f2bf(a) | ((unsigned int)f2bf(b) << 16);
}

// =========== KA: streaming 1x1 conv 64->8, [B,T,64] f32 -> [B,T,8] bf16 ===========
__global__ __launch_bounds__(256) void k_eeg1x1(const float* __restrict__ eeg,
                                                const float* __restrict__ w,
                                                const float* __restrict__ bias,
                                                unsigned short* __restrict__ x0b) {
    __shared__ float ws[512];
    __shared__ float bs[8];
    int tid = threadIdx.x;
    ws[tid]       = w[tid];
    ws[tid + 256] = w[tid + 256];
    if (tid < 8) bs[tid] = bias[tid];
    __syncthreads();

    int gt = blockIdx.x * 256 + tid;      // b*T + t
    const float* ep = eeg + (size_t)gt * 64;

    float acc[8];
#pragma unroll
    for (int c = 0; c < 8; ++c) acc[c] = bs[c];
#pragma unroll
    for (int i = 0; i < 64; i += 4) {
        float4 v = *(const float4*)(ep + i);
#pragma unroll
        for (int c = 0; c < 8; ++c) {
            const float* wp = ws + c * 64 + i;
            acc[c] += v.x * wp[0] + v.y * wp[1] + v.z * wp[2] + v.w * wp[3];
        }
    }
    uint4 p = { pk2(acc[0], acc[1]), pk2(acc[2], acc[3]),
                pk2(acc[4], acc[5]), pk2(acc[6], acc[7]) };
    *(uint4*)(x0b + (size_t)gt * 8) = p;   // 16B per t, coalesced
}

// =========== KB: eeg dilated stack 8->16->16->16 via MFMA, chunk=256 ===========
// grid (32 chunks, 64 b), 256 threads, ~24KB LDS -> 6 blocks/CU
__global__ __launch_bounds__(256) void k_estack(const unsigned short* __restrict__ x0b,
        const float* __restrict__ w1, const float* __restrict__ b1,
        const float* __restrict__ w2, const float* __restrict__ b2,
        const float* __restrict__ w3, const float* __restrict__ b3,
        unsigned short* __restrict__ x3b, float* __restrict__ nxp) {
    // LDS: x0T u16[304*8] @0 ; i1 u16[304*16] @4864 ; i2 u16[288*16] @14592 ; wred f32[64] @23808
    // aliases: Wst = i2 head (2560 u16 = 5120B); st3 u16[16*264] @0 (x0T+i1 dead by conv3)
    __shared__ __align__(16) unsigned char smem[24064];
    unsigned short* x0T = (unsigned short*)smem;
    unsigned short* i1  = (unsigned short*)(smem + 4864);
    unsigned short* i2  = (unsigned short*)(smem + 14592);
    float*          wred= (float*)(smem + 23808);
    unsigned short* st3 = (unsigned short*)smem;
    unsigned short* Wst = i2;

    int tid = threadIdx.x;
    int chunk = blockIdx.x, b = blockIdx.y;
    int wv = tid >> 6, lane = tid & 63, lm = lane & 15, lg = lane >> 4;

    int c0 = chunk * 256;
    int Lv = min(256, T3_ - c0);
    int n_in = Lv + 26, n1 = Lv + 24, n2 = Lv + 18;
    int nub1 = (n1 + 15) >> 4, nub2 = (n2 + 15) >> 4, nub3 = (Lv + 15) >> 4;

    // ---- stage weights (2560 bf16) ----
    for (int idx = tid; idx < 2560; idx += 256) {
        int arr = idx >> 9, e = idx & 511;
        int m = e >> 5, k5 = e & 31;
        float v = 0.f;
        if (arr == 0)      { int tap = k5 >> 3, ci = k5 & 7; if (tap < 3) v = w1[(m * 8 + ci) * 3 + tap]; }
        else if (arr == 1) { int tap = k5 >> 4, ci = k5 & 15; v = w2[(m * 16 + ci) * 3 + tap]; }
        else if (arr == 2) { if (k5 < 16) v = w2[(m * 16 + k5) * 3 + 2]; }
        else if (arr == 3) { int tap = k5 >> 4, ci = k5 & 15; v = w3[(m * 16 + ci) * 3 + tap]; }
        else               { if (k5 < 16) v = w3[(m * 16 + k5) * 3 + 2]; }
        Wst[idx] = f2bf(v);
    }
    // ---- stage x0 chunk rows [0,304): load valid, zero rest ----
    {
        const unsigned short* src = x0b + ((size_t)b * T_ + c0) * 8;
        uint4 z = {0, 0, 0, 0};
        for (int r = tid; r < 304; r += 256) {
            uint4 v = (r < n_in) ? *(const uint4*)(src + r * 8) : z;
            *(uint4*)(x0T + r * 8) = v;
        }
    }
    // ---- zero i1/i2 tails (NaN-safety) ----
    {
        int z1 = nub1 * 16;
        for (int idx = tid; idx < (304 - z1) * 8; idx += 256)
            ((unsigned int*)(i1 + z1 * 16))[idx] = 0;
        int z2 = nub2 * 16;   // never overlaps Wst (z2 >= 256 rows, Wst = rows 0..159)
        for (int idx = tid; idx < (288 - z2) * 8; idx += 256)
            ((unsigned int*)(i2 + z2 * 16))[idx] = 0;
    }
    __syncthreads();

    const bf16x8 W1f = *(const bf16x8*)(Wst +         lm * 32 + 8 * lg);
    const bf16x8 W2a = *(const bf16x8*)(Wst + 512  +  lm * 32 + 8 * lg);
    const bf16x8 W2b = *(const bf16x8*)(Wst + 1024 +  lm * 32 + 8 * lg);
    const bf16x8 W3a = *(const bf16x8*)(Wst + 1536 +  lm * 32 + 8 * lg);
    const bf16x8 W3b = *(const bf16x8*)(Wst + 2048 +  lm * 32 + 8 * lg);
    f32x4 c1v, c2v, c3v;
#pragma unroll
    for (int r = 0; r < 4; ++r) {
        int m = 4 * lg + r;
        c1v[r] = b1[m]; c2v[r] = b2[m]; c3v[r] = b3[m];
    }

    // ---- conv1 d=1 cin=8 (one MFMA) ----
    for (int ub = wv; ub < nub1; ub += 4) {
        int u = ub * 16 + lm;
        bf16x8 Ba = *(const bf16x8*)(x0T + (u + lg) * 8);   // lg==3 slot has W==0
        f32x4 acc = __builtin_amdgcn_mfma_f32_16x16x32_bf16(W1f, Ba, c1v, 0, 0, 0);
        uint2 pq = { pk2(fmaxf(acc[0], 0.f), fmaxf(acc[1], 0.f)),
                     pk2(fmaxf(acc[2], 0.f), fmaxf(acc[3], 0.f)) };
        *(uint2*)(i1 + u * 16 + lg * 4) = pq;
    }
    __syncthreads();

    // ---- conv2 d=3 ----
    for (int ub = wv; ub < nub2; ub += 4) {
        int u = ub * 16 + lm;
        int t3 = 3 * (lg >> 1);
        bf16x8 Ba = *(const bf16x8*)(i1 + (u + t3) * 16 + (lg & 1) * 8);
        bf16x8 Bb = *(const bf16x8*)(i1 + (u + 6 + t3) * 16 + (lg & 1) * 8);
        f32x4 acc = c2v;
        acc = __builtin_amdgcn_mfma_f32_16x16x32_bf16(W2a, Ba, acc, 0, 0, 0);
        acc = __builtin_amdgcn_mfma_f32_16x16x32_bf16(W2b, Bb, acc, 0, 0, 0);
        uint2 pq = { pk2(fmaxf(acc[0], 0.f), fmaxf(acc[1], 0.f)),
                     pk2(fmaxf(acc[2], 0.f), fmaxf(acc[3], 0.f)) };
        *(uint2*)(i2 + u * 16 + lg * 4) = pq;
    }
    __syncthreads();

    // ---- conv3 d=9 -> st3 + norm partials ----
    float nst[4] = {0.f, 0.f, 0.f, 0.f};
    for (int ub = wv; ub < nub3; ub += 4) {
        int u = ub * 16 + lm;
        int t9 = 9 * (lg >> 1);
        bf16x8 Ba = *(const bf16x8*)(i2 + (u + t9) * 16 + (lg & 1) * 8);
        bf16x8 Bb = *(const bf16x8*)(i2 + (u + 18 + t9) * 16 + (lg & 1) * 8);
        f32x4 acc = c3v;
        acc = __builtin_amdgcn_mfma_f32_16x16x32_bf16(W3a, Ba, acc, 0, 0, 0);
        acc = __builtin_amdgcn_mfma_f32_16x16x32_bf16(W3b, Bb, acc, 0, 0, 0);
        bool ok = u < Lv;
#pragma unroll
        for (int r = 0; r < 4; ++r) {
            float v = ok ? fmaxf(acc[r], 0.f) : 0.f;
            nst[r] += v * v;
            st3[(4 * lg + r) * 264 + u] = f2bf(v);
        }
    }
#pragma unroll
    for (int r = 0; r < 4; ++r) {
        float t = nst[r];
        t += __shfl_xor(t, 1); t += __shfl_xor(t, 2);
        t += __shfl_xor(t, 4); t += __shfl_xor(t, 8);
        nst[r] = t;
    }
    if (lm == 0) {
#pragma unroll
        for (int r = 0; r < 4; ++r) wred[wv * 16 + 4 * lg + r] = nst[r];
    }
    __syncthreads();

    if (tid < 16) {
        float s = wred[tid] + wred[16 + tid] + wred[32 + tid] + wred[48 + tid];
        nxp[((size_t)b * 16 + tid) * 32 + chunk] = s;
    }
    // ---- coalesced st3 -> x3b ----
    {
        unsigned short* dst = x3b + (size_t)(b * 16) * T3P + c0;
        for (int idx = tid; idx < 16 * 32; idx += 256) {
            int co = idx >> 5, off = (idx & 31) * 8;
            if (off + 8 <= Lv)
                *(uint4*)(dst + (size_t)co * T3P + off) = *(const uint4*)(st3 + co * 264 + off);
            else
                for (int k = off; k < Lv; ++k) dst[(size_t)co * T3P + k] = st3[co * 264 + k];
        }
        if (chunk == 31 && tid < 16)
            *(unsigned int*)(x3b + (size_t)(b * 16 + tid) * T3P + T3_) = 0;   // zero pad cols
    }
}

// =========== K4: stim fused MFMA stack + dot partials (unchanged, verified) ===========
__global__ __launch_bounds__(256) void k_stim(const float* __restrict__ stim,
                                              const float* __restrict__ w1, const float* __restrict__ b1,
                                              const float* __restrict__ w2, const float* __restrict__ b2,
                                              const float* __restrict__ w3, const float* __restrict__ b3,
                                              const unsigned short* __restrict__ x3b,
                                              float* __restrict__ dotp, float* __restrict__ nstp) {
    __shared__ __align__(16) unsigned char smem[41600];
    float*          sinb = (float*)smem;
    unsigned short* Wl   = (unsigned short*)(smem + 2176);
    unsigned short* i1   = (unsigned short*)(smem + 6272);
    unsigned short* i2   = (unsigned short*)(smem + 24192);
    unsigned short* s3   = i1;

    int tid  = threadIdx.x;
    int bs   = blockIdx.x;
    int G    = blockIdx.y;
    int wv   = tid >> 6;
    int lane = tid & 63;
    int lm   = lane & 15;
    int lg   = lane >> 4;

    for (int idx = tid; idx < 2048; idx += 256) {
        int arr = idx >> 9, e = idx & 511;
        int m = e >> 5, k5 = e & 31;
        int ci = k5 & 15, tap = k5 >> 4;
        float v;
        if (arr == 0)      v = w2[(m * 16 + ci) * 3 + tap];
        else if (arr == 1) v = (k5 < 16) ? w2[(m * 16 + k5) * 3 + 2] : 0.f;
        else if (arr == 2) v = w3[(m * 16 + ci) * 3 + tap];
        else               v = (k5 < 16) ? w3[(m * 16 + k5) * 3 + 2] : 0.f;
        Wl[idx] = f2bf(v);
    }
    __syncthreads();
    const bf16x8 W2a = *(const bf16x8*)(Wl +         lm * 32 + 8 * lg);
    const bf16x8 W2b = *(const bf16x8*)(Wl + 512  +  lm * 32 + 8 * lg);
    const bf16x8 W3a = *(const bf16x8*)(Wl + 1024 +  lm * 32 + 8 * lg);
    const bf16x8 W3b = *(const bf16x8*)(Wl + 1536 +  lm * 32 + 8 * lg);
    f32x4 cin2, cin3;
#pragma unroll
    for (int r = 0; r < 4; ++r) { cin2[r] = b2[4 * lg + r]; cin3[r] = b3[4 * lg + r]; }

    const float* seq = stim + (size_t)bs * T_;
    int b16 = (bs >> 3) * 16;

    f32x4 dacc;
#pragma unroll
    for (int r = 0; r < 4; ++r) dacc[r] = 0.f;
    float nst[4] = {0.f, 0.f, 0.f, 0.f};

    for (int cc = 0; cc < 4; ++cc) {
        int c0 = (G * 4 + cc) * 512;
        int Lv = min(512, T3_ - c0);
        int n1 = Lv + 24;

        __syncthreads();

        for (int t = tid; t < Lv + 26; t += 256) sinb[t] = seq[c0 + t];
        __syncthreads();

        for (int v = tid; v < n1; v += 256) {
            float s0 = sinb[v], s1 = sinb[v + 1], s2 = sinb[v + 2];
            float a[16];
#pragma unroll
            for (int co = 0; co < 16; ++co)
                a[co] = fmaxf(b1[co] + s0 * w1[co * 3] + s1 * w1[co * 3 + 1] + s2 * w1[co * 3 + 2], 0.f);
            uint4 p0, p1;
            p0.x = pk2(a[0], a[1]);   p0.y = pk2(a[2], a[3]);
            p0.z = pk2(a[4], a[5]);   p0.w = pk2(a[6], a[7]);
            p1.x = pk2(a[8], a[9]);   p1.y = pk2(a[10], a[11]);
            p1.z = pk2(a[12], a[13]); p1.w = pk2(a[14], a[15]);
            *(uint4*)(i1 + v * 16)     = p0;
            *(uint4*)(i1 + v * 16 + 8) = p1;
        }
        for (int z = tid; z < (560 - n1) * 8; z += 256)
            ((unsigned int*)i1)[n1 * 8 + z] = 0;
        __syncthreads();

        for (int ub = wv; ub < 34; ub += 4) {
            int u = ub * 16 + lm;
            int t3 = 3 * (lg >> 1);
            bf16x8 Ba = *(const bf16x8*)(i1 + (u + t3) * 16 + (lg & 1) * 8);
            bf16x8 Bb = *(const bf16x8*)(i1 + (u + 6 + t3) * 16 + (lg & 1) * 8);
            f32x4 acc = cin2;
            acc = __builtin_amdgcn_mfma_f32_16x16x32_bf16(W2a, Ba, acc, 0, 0, 0);
            acc = __builtin_amdgcn_mfma_f32_16x16x32_bf16(W2b, Bb, acc, 0, 0, 0);
            uint2 pq;
            pq.x = pk2(fmaxf(acc[0], 0.f), fmaxf(acc[1], 0.f));
            pq.y = pk2(fmaxf(acc[2], 0.f), fmaxf(acc[3], 0.f));
            *(uint2*)(i2 + u * 16 + lg * 4) = pq;
        }
        __syncthreads();

        for (int ub = wv; ub < 32; ub += 4) {
            int u = ub * 16 + lm;
            int t9 = 9 * (lg >> 1);
            bf16x8 Ba = *(const bf16x8*)(i2 + (u + t9) * 16 + (lg & 1) * 8);
            bf16x8 Bb = *(const bf16x8*)(i2 + (u + 18 + t9) * 16 + (lg & 1) * 8);
            f32x4 acc = cin3;
            acc = __builtin_amdgcn_mfma_f32_16x16x32_bf16(W3a, Ba, acc, 0, 0, 0);
            acc = __builtin_amdgcn_mfma_f32_16x16x32_bf16(W3b, Bb, acc, 0, 0, 0);
            bool ok = (u < Lv);
#pragma unroll
            for (int r = 0; r < 4; ++r) {
                float v = ok ? fmaxf(acc[r], 0.f) : 0.f;
                nst[r] += v * v;
                s3[(4 * lg + r) * 536 + u] = f2bf(v);
            }
        }
        __syncthreads();

#pragma unroll
        for (int kk = 0; kk < 4; ++kk) {
            int tl = wv * 128 + kk * 32 + 8 * lg;
            bf16x8 Af = *(const bf16x8*)(s3 + lm * 536 + tl);
            int tg = c0 + tl;
            int tc = (tg > 8160) ? 0 : tg;
            bf16x8 Bf = *(const bf16x8*)(x3b + (size_t)(b16 + lm) * T3P + tc);
            dacc = __builtin_amdgcn_mfma_f32_16x16x32_bf16(Af, Bf, dacc, 0, 0, 0);
        }
    }

#pragma unroll
    for (int r = 0; r < 4; ++r) {
        float t = nst[r];
        t += __shfl_xor(t, 1); t += __shfl_xor(t, 2);
        t += __shfl_xor(t, 4); t += __shfl_xor(t, 8);
        nst[r] = t;
    }
    int ob = (bs * 4 + G) * 4 + wv;
    *(f32x4*)(dotp + (size_t)ob * 256 + lane * 4) = dacc;
    if (lm == 0) {
#pragma unroll
        for (int r = 0; r < 4; ++r) nstp[(size_t)ob * 16 + 4 * lg + r] = nst[r];
    }
}

// =========== K5: reduce partials, cosine, linear head ===========
__global__ __launch_bounds__(256) void k_head(const float* __restrict__ dotp,
                                              const float* __restrict__ nstp,
                                              const float* __restrict__ nxp,
                                              const float* __restrict__ wlin,
                                              const float* __restrict__ blin,
                                              float* __restrict__ out) {
    int bs = blockIdx.x, tid = threadIdx.x;
    int b = bs >> 3;
    __shared__ float nxv[16];
    if (tid < 16) {
        float s = 0.f;
#pragma unroll
        for (int ch = 0; ch < 32; ++ch) s += nxp[((size_t)b * 16 + tid) * 32 + ch];
        nxv[tid] = fmaxf(sqrtf(s), EPS_);
    }
    __syncthreads();
    int i = 4 * (tid >> 6) + (tid & 3);
    int j = (tid >> 2) & 15;
    float dot = 0.f, ss = 0.f;
#pragma unroll
    for (int gw = 0; gw < 16; ++gw) {
        dot += dotp[(size_t)(bs * 16 + gw) * 256 + tid];
        ss  += nstp[(size_t)(bs * 16 + gw) * 16 + i];
    }
    float nstv = fmaxf(sqrtf(ss), EPS_);
    float val = dot / (nstv * nxv[j]) * wlin[i * 16 + j];
#pragma unroll
    for (int m = 32; m > 0; m >>= 1) val += __shfl_down(val, m, 64);
    __shared__ float rd[4];
    if ((tid & 63) == 0) rd[tid >> 6] = val;
    __syncthreads();
    if (tid == 0) out[bs] = rd[0] + rd[1] + rd[2] + rd[3] + blin[0];
}

extern "C" void kernel_launch(void* const* d_in, const int* in_sizes, int n_in,
                              void* d_out, int out_size, void* d_ws, size_t ws_size,
                              hipStream_t stream) {
    const float* eeg   = (const float*)d_in[0];
    const float* stim  = (const float*)d_in[1];
    const float* w_eeg = (const float*)d_in[2];
    const float* b_eeg = (const float*)d_in[3];
    const float* w_e1  = (const float*)d_in[4];
    const float* b_e1  = (const float*)d_in[5];
    const float* w_e2  = (const float*)d_in[6];
    const float* b_e2  = (const float*)d_in[7];
    const float* w_e3  = (const float*)d_in[8];
    const float* b_e3  = (const float*)d_in[9];
    const float* w_s1  = (const float*)d_in[10];
    const float* b_s1  = (const float*)d_in[11];
    const float* w_s2  = (const float*)d_in[12];
    const float* b_s2  = (const float*)d_in[13];
    const float* w_s3  = (const float*)d_in[14];
    const float* b_s3  = (const float*)d_in[15];
    const float* w_lin = (const float*)d_in[16];
    const float* b_lin = (const float*)d_in[17];

    unsigned char* ws = (unsigned char*)d_ws;
    unsigned short* x3b  = (unsigned short*)ws;                 // 16,728,064 B
    float*          nxp  = (float*)(ws + 16728064);             // 131,072 B
    float*          dotp = (float*)(ws + 16859136);             // 8,388,608 B
    float*          nstp = (float*)(ws + 25247744);             // 524,288 B
    unsigned short* x0b  = (unsigned short*)(ws + 25772032);    // 8,388,608 B
    float*          out  = (float*)d_out;

    k_eeg1x1<<<(B_ * T_) / 256, 256, 0, stream>>>(eeg, w_eeg, b_eeg, x0b);
    k_estack<<<dim3(32, B_), 256, 0, stream>>>(x0b, w_e1, b_e1, w_e2, b_e2,
                                               w_e3, b_e3, x3b, nxp);
    k_stim<<<dim3(B_ * S_, 4), 256, 0, stream>>>(stim, w_s1, b_s1, w_s2, b_s2, w_s3, b_s3,
                                                 x3b, dotp, nstp);
    k_head<<<B_ * S_, 256, 0, stream>>>(dotp, nstp, nxp, w_lin, b_lin, out);
}